// Round 2
// baseline (57.039 us; speedup 1.0000x reference)
//
#include <hip/hip_runtime.h>

// out[j,i] = sum_k exp(-(x_k - i/512)^2 * 5000) * exp(-(y_k - j/512)^2 * 5000)
// sigma = 0.01 -> 5.12 px: a point only influences +/-33 px (tail < 1e-9).
//
// v3 (on top of v2's 16x16 tiles / 1024 blocks):
//  - staging tiles TRANSPOSED to [pixel][k] with +4 pad (144 B rows,
//    16B-aligned, <=2-way bank aliasing = free): accumulate reads float4,
//    16 ds_read_b128 per chunk instead of 64 ds_read_b32 (4x fewer LDS instrs)
//  - chunk DOUBLE-BUFFERING: one barrier per chunk (was 2), and the next
//    chunk's __expf staging overlaps the current chunk's FMA loop
//  - per-curve control-point bbox cull (convex hull property): each eval
//    wave covers exactly one curve, so the skip is wave-uniform; far tiles
//    skip nearly all de Casteljau work
// Sparse gather: evaluate surviving curves' 128 points, cull to the tile's
// +/-33px window, wave-ballot compaction into LDS (1 atomic/wave),
// sentinel-pad to a CH multiple so staging + accumulate are branch-free.
// Single dispatch, direct full-coverage store (empty tiles: acc=0).

constexpr int RES_ = 512;
constexpr int TILE = 16;               // output tile edge
constexpr int NPTS = 1024;
constexpr int CH   = 32;               // points staged per chunk
constexpr int CHP  = CH + 4;           // padded k-stride (36 words = 144 B)
constexpr float RAD = 33.0f / 512.0f;  // truncation radius (33 px)
constexpr float SENTINEL = 1.0e3f;     // far away -> exp flushes to exact 0

__global__ __launch_bounds__(256)
void bezier_sparse16(const float* __restrict__ curves, float* __restrict__ out) {
    __shared__ float lx[NPTS + CH], ly[NPTS + CH];   // compacted + pad (8.4 KB)
    __shared__ int count;
    __shared__ int ovl[8];                           // per-curve bbox overlap
    __shared__ __align__(16) float ex_s[2][TILE][CHP];   // 4.6 KB
    __shared__ __align__(16) float ey_s[2][TILE][CHP];   // 4.6 KB

    const int tid  = threadIdx.x;
    const int lane = tid & 63;
    const int ibase = blockIdx.x * TILE;   // output columns i
    const int jbase = blockIdx.y * TILE;   // output rows j

    const float xlo = (float)ibase * (1.0f/512.0f) - RAD;
    const float xhi = (float)(ibase + TILE - 1) * (1.0f/512.0f) + RAD;
    const float ylo = (float)jbase * (1.0f/512.0f) - RAD;
    const float yhi = (float)(jbase + TILE - 1) * (1.0f/512.0f) + RAD;

    if (tid == 0) count = 0;
    if (tid < 8) {
        // control-point bbox (curve is inside its control hull)
        const float* cp = curves + tid * 8;
        float bx0 = fminf(fminf(cp[0], cp[2]), fminf(cp[4], cp[6]));
        float bx1 = fmaxf(fmaxf(cp[0], cp[2]), fmaxf(cp[4], cp[6]));
        float by0 = fminf(fminf(cp[1], cp[3]), fminf(cp[5], cp[7]));
        float by1 = fmaxf(fmaxf(cp[1], cp[3]), fmaxf(cp[5], cp[7]));
        ovl[tid] = (bx1 > xlo && bx0 < xhi && by1 > ylo && by0 < yhi);
    }
    __syncthreads();

    // --- evaluate 4 Bezier points/thread (de Casteljau), ballot-compact ---
    // Each 64-lane wave within an iteration maps to a single curve
    // (p>>7 is constant over 64 consecutive p), so the bbox skip and the
    // ballot/shfl sequence are wave-uniform.
#pragma unroll
    for (int e = 0; e < NPTS / 256; ++e) {
        int p = e * 256 + tid;
        int c = p >> 7;                            // curve 0..7 (wave-uniform)
        if (!ovl[c]) continue;
        float t = (float)(p & 127) * (1.0f / 127.0f);
        const float* cp = curves + c * 8;
        float p0x = cp[0], p0y = cp[1];
        float p1x = cp[2], p1y = cp[3];
        float p2x = cp[4], p2y = cp[5];
        float p3x = cp[6], p3y = cp[7];
        float a01x = p0x + (p1x - p0x) * t, a01y = p0y + (p1y - p0y) * t;
        float a12x = p1x + (p2x - p1x) * t, a12y = p1y + (p2y - p1y) * t;
        float a23x = p2x + (p3x - p2x) * t, a23y = p2y + (p3y - p2y) * t;
        float qax = a01x + (a12x - a01x) * t, qay = a01y + (a12y - a01y) * t;
        float qbx = a12x + (a23x - a12x) * t, qby = a12y + (a23y - a12y) * t;
        float X = qax + (qbx - qax) * t;
        float Y = qay + (qby - qay) * t;

        bool keep = (X > xlo && X < xhi && Y > ylo && Y < yhi);
        unsigned long long mask = __ballot(keep);
        if (mask) {
            int nsurv  = __popcll(mask);
            int prefix = __popcll(mask & ((1ull << lane) - 1ull));
            int leader = __ffsll((long long)mask) - 1;
            int base_i = 0;
            if (lane == leader)
                base_i = atomicAdd(&count, nsurv);      // 1 atomic per wave
            base_i = __shfl(base_i, leader);
            if (keep) {
                lx[base_i + prefix] = X;
                ly[base_i + prefix] = Y;
            }
        }
    }
    __syncthreads();
    const int M = count;

    // --- sentinel-pad survivor list up to next CH multiple (branch-free) ---
    if (tid < CH) {
        lx[M + tid] = SENTINEL;
        ly[M + tid] = SENTINEL;
    }
    __syncthreads();

    // one output pixel per thread
    const int it = tid & 15, jt = tid >> 4;
    float acc0 = 0.f, acc1 = 0.f, acc2 = 0.f, acc3 = 0.f;

    const int nch = (M + CH - 1) / CH;             // chunks (may be 0)

    // stage chunk at `base` into buffer b: [pixel][k] transposed layout
    auto stage = [&](int b, int base) {
#pragma unroll
        for (int e = 0; e < (CH * TILE) / 256; ++e) {   // 2 slots/thread
            int idx = e * 256 + tid;
            int kk  = idx >> 4;                    // TILE == 16
            int ii  = idx & 15;
            float xv = lx[base + kk], yv = ly[base + kk];
            float dx = xv - (float)(ibase + ii) * (1.0f / 512.0f);
            float dy = yv - (float)(jbase + ii) * (1.0f / 512.0f);
            ex_s[b][ii][kk] = __expf(dx * dx * -5000.0f);   // sentinel -> 0
            ey_s[b][ii][kk] = __expf(dy * dy * -5000.0f);
        }
    };

    if (nch > 0) stage(0, 0);
    for (int c = 0; c < nch; ++c) {
        __syncthreads();                  // buf[c&1] staged; prev reads done
        if (c + 1 < nch) stage((c + 1) & 1, (c + 1) * CH);
        const int b = c & 1;
        const float4* ax4 = reinterpret_cast<const float4*>(&ex_s[b][it][0]);
        const float4* ay4 = reinterpret_cast<const float4*>(&ey_s[b][jt][0]);
#pragma unroll
        for (int k4 = 0; k4 < CH / 4; k4 += 2) {
            float4 ax = ax4[k4],     ay = ay4[k4];
            float4 bx = ax4[k4 + 1], by = ay4[k4 + 1];
            acc0 = fmaf(ax.x, ay.x, acc0); acc1 = fmaf(ax.y, ay.y, acc1);
            acc2 = fmaf(ax.z, ay.z, acc2); acc3 = fmaf(ax.w, ay.w, acc3);
            acc0 = fmaf(bx.x, by.x, acc0); acc1 = fmaf(bx.y, by.y, acc1);
            acc2 = fmaf(bx.z, by.z, acc2); acc3 = fmaf(bx.w, by.w, acc3);
        }
    }

    // --- full-coverage store (empty tiles write 0, no memset needed) ---
    out[(size_t)(jbase + jt) * RES_ + (ibase + it)] = (acc0 + acc1) + (acc2 + acc3);
}

extern "C" void kernel_launch(void* const* d_in, const int* in_sizes, int n_in,
                              void* d_out, int out_size, void* d_ws, size_t ws_size,
                              hipStream_t stream) {
    const float* curves = (const float*)d_in[0];
    float* out = (float*)d_out;

    dim3 grid(RES_ / TILE, RES_ / TILE);           // (32, 32) = 1024 blocks
    bezier_sparse16<<<grid, dim3(256), 0, stream>>>(curves, out);
}